// Round 8
// baseline (141.926 us; speedup 1.0000x reference)
//
#include <hip/hip_runtime.h>
#include <hip/hip_bf16.h>

// RPEMultiHeadAttention, MI355X (gfx950).
// Math: rel-pos terms (attn2/attn3) are constant along the softmax axis ->
// softmax shift-invariance -> dead. Reference == plain MHA, scale 1/sqrt(192).
// All external I/O is float32; intermediates bf16 (MFMA), f32 accumulate.
//
// v18r = v18 resubmission (round-7 bench died with "container failed twice",
// the same infra signature as round 2, which passed on identical resubmit).
// v18 = occupancy attack. v17 post-mortem: 1-barrier dbuf regressed (~+2us);
// no pipe >35% busy -> latency-bound from lockstep waves, fix = MORE waves.
//  - flash QBLK 128->64 (grid 64x16): 8 waves = 4 q-groups x 2 kh, each wave
//    ONE 16-row set. Per-wave regs halve (Sf16 Of16 qf8 Lf4) -> natural ~90;
//    __launch_bounds__(512,6) caps 85 (deficit ~0-10, remat-able; v15's fatal
//    deficit was 31). LDS 35840 B (K[128][72]+V[64][136], single-buf v16
//    2-barrier loop) -> 3 blocks/CU = 24 waves (+50% latency hiding).
//  - epilogue: kh=1 sends Of/Lf via LDS; kh=0 combines+normalizes to Pe;
//    BOTH kh waves project (each 2 of 4 nt-cols) + atomics.
// Retained: sigma-permuted PV (P in regs), ones-MFMA L, swapped QK^T, exp2.
// Tripwire: FETCH>50MB => spill regression, revert to v16.
// Harness note: ~2x 256MiB poison fills (~86 us) dominate e2e.

#define N_HEAD 8
#define SEQ    1024
#define SC2    0.10411804386480816f  // (1/sqrt(192)) * log2(e)

typedef __hip_bfloat16 bf16;
typedef __bf16 bf16x8 __attribute__((ext_vector_type(8)));
typedef __bf16 bf16x4 __attribute__((ext_vector_type(4)));
typedef float  f32x4  __attribute__((ext_vector_type(4)));

// ---------------------------------------------------------------------------
// Kernel 1: q1/k1/v1 = X @ W + b via MFMA (unchanged from v16/v17).
// ---------------------------------------------------------------------------
__global__ __launch_bounds__(256)
void qkv_mfma_kernel(const float* __restrict__ Xq, const float* __restrict__ Xk,
                     const float* __restrict__ Xv,
                     const float* __restrict__ Wq, const float* __restrict__ Wk,
                     const float* __restrict__ Wv,
                     const float* __restrict__ bq, const float* __restrict__ bk,
                     const float* __restrict__ bv,
                     const float* __restrict__ bo, float* __restrict__ out,
                     bf16* __restrict__ Qh, bf16* __restrict__ Kh,
                     bf16* __restrict__ Vt)
{
    const int rt    = blockIdx.x;   // rows rt*128 .. +127 of [8192]
    const int ct    = blockIdx.y;   // head (cols ct*64 .. +63)
    const int which = blockIdx.z;   // 0=q 1=k 2=v

    const float* __restrict__ X    = which == 0 ? Xq : (which == 1 ? Xk : Xv);
    const float* __restrict__ W    = which == 0 ? Wq : (which == 1 ? Wk : Wv);
    const float* __restrict__ bias = which == 0 ? bq : (which == 1 ? bk : bv);

    __shared__ __align__(16) bf16 Xs [128 * 72];  // A tiles [m][k]; reused as C overlay
    __shared__ __align__(16) bf16 Wts[64 * 72];   // B tiles [n][k]
    __shared__ float Bs[64];

    const int tid  = threadIdx.x;
    const int w4   = tid >> 6;
    const int lane = tid & 63;
    const int t16  = lane & 15;
    const int quad = lane >> 4;

    if (tid < 64) Bs[tid] = bias[ct * 64 + tid];
    // stage X (f32 -> bf16): 128x64, coalesced float4 reads
    for (int i = tid; i < 2048; i += 256) {
        const int r = i >> 4, c4 = (i & 15) << 2;
        const float4 v = *(const float4*)&X[(size_t)(rt * 128 + r) * 64 + c4];
        bf16 t[4] = {__float2bfloat16(v.x), __float2bfloat16(v.y),
                     __float2bfloat16(v.z), __float2bfloat16(v.w)};
        *(bf16x4*)&Xs[r * 72 + c4] = *(bf16x4*)t;
    }
    // stage W^T slice: Wts[n][k] = W[k][ct*64+n], coalesced float4 row reads
    for (int i = tid; i < 1024; i += 256) {
        const int k = i >> 4, n4 = (i & 15) << 2;
        const float4 w = *(const float4*)&W[(size_t)k * 512 + ct * 64 + n4];
        Wts[(n4 + 0) * 72 + k] = __float2bfloat16(w.x);
        Wts[(n4 + 1) * 72 + k] = __float2bfloat16(w.y);
        Wts[(n4 + 2) * 72 + k] = __float2bfloat16(w.z);
        Wts[(n4 + 3) * 72 + k] = __float2bfloat16(w.w);
    }
    // bias-init out for flash's atomic accumulation (runs before flash in-stream)
    if (which == 0 && ct == 0) {
        for (int i = tid; i < 2048; i += 256) {
            const int r = i >> 4, c4 = (i & 15) << 2;
            *(float4*)&out[(size_t)(rt * 128 + r) * 64 + c4] = *(const float4*)&bo[c4];
        }
    }
    __syncthreads();

    // B fragments (shared across both row-sets)
    bf16x8 bf0[4], bf1[4];
#pragma unroll
    for (int nt = 0; nt < 4; nt++) {
        bf0[nt] = *(const bf16x8*)&Wts[(nt * 16 + t16) * 72 + 0  + quad * 8];
        bf1[nt] = *(const bf16x8*)&Wts[(nt * 16 + t16) * 72 + 32 + quad * 8];
    }

    f32x4 acc[2][4];
#pragma unroll
    for (int rs = 0; rs < 2; rs++) {
        const int m = rs * 64 + w4 * 16 + t16;
        const bf16x8 af0 = *(const bf16x8*)&Xs[m * 72 + 0  + quad * 8];
        const bf16x8 af1 = *(const bf16x8*)&Xs[m * 72 + 32 + quad * 8];
#pragma unroll
        for (int nt = 0; nt < 4; nt++) {
            acc[rs][nt] = (f32x4){0.f, 0.f, 0.f, 0.f};
            acc[rs][nt] = __builtin_amdgcn_mfma_f32_16x16x32_bf16(af0, bf0[nt], acc[rs][nt], 0, 0, 0);
            acc[rs][nt] = __builtin_amdgcn_mfma_f32_16x16x32_bf16(af1, bf1[nt], acc[rs][nt], 0, 0, 0);
        }
    }

    const int b     = rt >> 3;
    const int sbase = (rt & 7) * 128;

    __syncthreads();   // all waves done reading Xs/Wts -> overlay is safe

    if (which < 2) {
        // Q/K: stage C into LDS overlay [128 r][72], then contiguous stores
        bf16* Cs = Xs;
        const float sc = (which == 0) ? SC2 : 1.0f;   // fold softmax scale into Q
#pragma unroll
        for (int rs = 0; rs < 2; rs++)
#pragma unroll
            for (int nt = 0; nt < 4; nt++)
#pragma unroll
                for (int rr = 0; rr < 4; rr++) {
                    const int row = rs * 64 + w4 * 16 + quad * 4 + rr;
                    Cs[row * 72 + nt * 16 + t16] =
                        __float2bfloat16((acc[rs][nt][rr] + Bs[nt * 16 + t16]) * sc);
                }
        __syncthreads();
        bf16* O = which == 0 ? Qh : Kh;
        for (int i = tid; i < 1024; i += 256) {
            const int r = i >> 3, c8 = (i & 7) << 3;
            *(bf16x8*)&O[(((size_t)b * N_HEAD + ct) * SEQ + sbase + r) * 64 + c8] =
                *(const bf16x8*)&Cs[r * 72 + c8];
        }
    } else {
        // V: transpose via LDS overlay, then coalesced stores
        bf16* VtS = Xs;   // [64 c][136 r]
#pragma unroll
        for (int rs = 0; rs < 2; rs++)
#pragma unroll
            for (int nt = 0; nt < 4; nt++)
#pragma unroll
                for (int rr = 0; rr < 4; rr++) {
                    const int rloc = rs * 64 + w4 * 16 + quad * 4 + rr;
                    VtS[(nt * 16 + t16) * 136 + rloc] =
                        __float2bfloat16(acc[rs][nt][rr] + Bs[nt * 16 + t16]);
                }
        __syncthreads();
        for (int i = tid; i < 1024; i += 256) {
            const int c = i >> 4, r8 = (i & 15) << 3;
            *(bf16x8*)&Vt[(((size_t)b * N_HEAD + ct) * 64 + c) * SEQ + sbase + r8] =
                *(const bf16x8*)&VtS[c * 136 + r8];
        }
    }
}

// ---------------------------------------------------------------------------
// Kernel 2: flash attention + fused out-proj. QBLK=64.
// Grid (bh=64, qt=16): XCD = bh%8, all qt-blocks of one (b,h) share an XCD L2.
// Block = 512 threads = 8 waves = {4 q-groups of 16 rows} x {2 k-halves}.
// Each wave: ONE row-set. Swapped QK^T: Sf[nt] holds S[kv=kh*64+nt*16+quad*4
// +rr][q=t16]. Sigma-PV: A-frag = lane's own exp2 regs; V = 4x ds_read_b64.
// l via ones-MFMA (Lf[rr] keyed q=quad*4+rr == Of keying).
// LDS 35840 B: Ks[128][72] + Vs[64][136], single-buffered, 2 barriers/iter.
// Epilogue: kh=1 sends Of/Lf; kh=0 combines+normalizes -> Pe (overlays dead
// Ks after barrier); both kh waves project 2 nt-cols each + atomics.
// __launch_bounds__(512,6): 85-VGPR cap -> 3 blocks/CU (24 waves).
// ---------------------------------------------------------------------------
__global__ __launch_bounds__(512, 6)
void flash_attn_kernel(const bf16* __restrict__ Qh, const bf16* __restrict__ Kh,
                       const bf16* __restrict__ Vt, const float* __restrict__ Wo,
                       float* __restrict__ out)
{
    const int bhx  = blockIdx.x;    // 0..63
    const int qt   = blockIdx.y;    // 0..15 (64 q-rows each)
    const int b    = bhx >> 3;
    const int h    = bhx & 7;
    const int tid  = threadIdx.x;
    const int wave = tid >> 6;      // 0..7
    const int w4   = wave & 3;      // q-group (16 rows)
    const int kh   = wave >> 2;     // k-half of the 128-kv tile
    const int lane = tid & 63;
    const int t16  = lane & 15;
    const int quad = lane >> 4;

    const size_t bh = (size_t)b * N_HEAD + h;
    const bf16* __restrict__ Qp  = Qh + bh * (SEQ * 64);  // [1024][64], pre-scaled
    const bf16* __restrict__ Kp  = Kh + bh * (SEQ * 64);  // [1024][64]
    const bf16* __restrict__ Vtp = Vt + bh * (64 * SEQ);  // [64][1024]

    __shared__ __align__(16) bf16 smem[17920];            // 35840 B
    bf16* Ks = smem;                 // [128][72]  : elems [0, 9216)
    bf16* Vs = smem + 9216;          // [64][136]  : elems [9216, 17920)

    // Q fragments for this wave's 16 rows
    const int qrow = qt * 64 + w4 * 16 + t16;
    const bf16x8 qf0 = *(const bf16x8*)(Qp + (size_t)qrow * 64 + 0  + quad * 8);
    const bf16x8 qf1 = *(const bf16x8*)(Qp + (size_t)qrow * 64 + 32 + quad * 8);

    // constant all-ones B fragment for the l row-sum MFMA
    bf16x8 vones;
#pragma unroll
    for (int j = 0; j < 8; j++) vones[j] = (__bf16)1.0f;

    f32x4 Of[4];
    f32x4 Lf;
#pragma unroll
    for (int nt = 0; nt < 4; nt++) Of[nt] = (f32x4){0.f, 0.f, 0.f, 0.f};
    Lf = (f32x4){0.f, 0.f, 0.f, 0.f};

    // ---- staging: each thread owns 4 fixed 16B chunks of the 128-kv tile ----
    const int kr = tid >> 3;             // 0..63   (K rows, 2 passes)
    const int kc = (tid & 7) << 3;       // 0..56
    const int vd = tid >> 4;             // 0..31   (V d-rows, 2 passes)
    const int vc = (tid & 15) << 3;      // 0..120
    bf16x8 preK0, preK1, preV0, preV1;
#define LOAD_TILES(kt_)                                                           \
    do {                                                                          \
        const size_t kv0 = (size_t)(kt_) * 128;                                   \
        preK0 = *(const bf16x8*)&Kp [(kv0 + kr) * 64 + kc];                       \
        preK1 = *(const bf16x8*)&Kp [(kv0 + 64 + kr) * 64 + kc];                  \
        preV0 = *(const bf16x8*)&Vtp[(size_t)vd * SEQ + kv0 + vc];                \
        preV1 = *(const bf16x8*)&Vtp[(size_t)(vd + 32) * SEQ + kv0 + vc];         \
    } while (0)

    LOAD_TILES(0);

    for (int kt = 0; kt < 8; kt++) {
        *(bf16x8*)&Ks[kr * 72 + kc]        = preK0;
        *(bf16x8*)&Ks[(64 + kr) * 72 + kc] = preK1;
        *(bf16x8*)&Vs[vd * 136 + vc]        = preV0;
        *(bf16x8*)&Vs[(vd + 32) * 136 + vc] = preV1;
        __syncthreads();

        if (kt < 7) LOAD_TILES(kt + 1);   // latency hidden behind compute below

        // ---- Phase A: S^T = K Q^T (swapped), this wave's k-half ----
        // Sf[nt] lane layout: q=t16 (A-m), kv=kh*64+nt*16+quad*4+rr (D-row)
        f32x4 Sf[4];
        __builtin_amdgcn_s_setprio(1);
#pragma unroll
        for (int nt = 0; nt < 4; nt++) {
            const int krow = (kh * 64 + nt * 16 + t16) * 72;
            const bf16x8 kf0 = *(const bf16x8*)&Ks[krow + 0  + quad * 8];
            const bf16x8 kf1 = *(const bf16x8*)&Ks[krow + 32 + quad * 8];
            Sf[nt] = (f32x4){0.f, 0.f, 0.f, 0.f};
            Sf[nt] = __builtin_amdgcn_mfma_f32_16x16x32_bf16(kf0, qf0, Sf[nt], 0, 0, 0);
            Sf[nt] = __builtin_amdgcn_mfma_f32_16x16x32_bf16(kf1, qf1, Sf[nt], 0, 0, 0);
        }
        __builtin_amdgcn_s_setprio(0);

        // ---- Phase B: p = exp2(S), packed in-register sigma-ordered ----
        // slot (quad,j) <-> kv_local = (j>=4)*16 + quad*4 + (j&3) (+32 for hi)
        bf16 tl[8], th[8];
#pragma unroll
        for (int nt = 0; nt < 4; nt++)
#pragma unroll
            for (int rr = 0; rr < 4; rr++) {
                const float p = __builtin_amdgcn_exp2f(Sf[nt][rr]);
                if (nt < 2) tl[nt * 4 + rr]       = __float2bfloat16(p);
                else        th[(nt - 2) * 4 + rr] = __float2bfloat16(p);
            }
        const bf16x8 pfl = *(bf16x8*)tl;
        const bf16x8 pfh = *(bf16x8*)th;

        // ---- Phase C: O += P V (+ l via ones MFMA); V read sigma-ordered ----
        __builtin_amdgcn_s_setprio(1);
#pragma unroll
        for (int nt = 0; nt < 4; nt++) {
            const int vrow = (nt * 16 + t16) * 136 + kh * 64;
            bf16 vl[8], vh[8];
            *(bf16x4*)&vl[0] = *(const bf16x4*)&Vs[vrow + 0  + quad * 4];
            *(bf16x4*)&vl[4] = *(const bf16x4*)&Vs[vrow + 16 + quad * 4];
            *(bf16x4*)&vh[0] = *(const bf16x4*)&Vs[vrow + 32 + quad * 4];
            *(bf16x4*)&vh[4] = *(const bf16x4*)&Vs[vrow + 48 + quad * 4];
            Of[nt] = __builtin_amdgcn_mfma_f32_16x16x32_bf16(pfl, *(const bf16x8*)vl, Of[nt], 0, 0, 0);
            Of[nt] = __builtin_amdgcn_mfma_f32_16x16x32_bf16(pfh, *(const bf16x8*)vh, Of[nt], 0, 0, 0);
        }
        Lf = __builtin_amdgcn_mfma_f32_16x16x32_bf16(pfl, vones, Lf, 0, 0, 0);
        Lf = __builtin_amdgcn_mfma_f32_16x16x32_bf16(pfh, vones, Lf, 0, 0, 0);
        __builtin_amdgcn_s_setprio(0);
        __syncthreads();
    }
#undef LOAD_TILES

    // ---- epilogue ----
    // Overlay map (bytes from smem base, all regions dead vs main loop):
    //   Xch f32 [4 g][64 lane][17] : [0, 17408)
    //   Lch f32x4 [4 g][64 lane]   : [17408, 21504)
    //   WoS bf16 [64][72]          : [21504, 30720)
    //   Pe  bf16 [4 g][16*72]      : [0, 9216)   -- after 2nd barrier
    float* Xch = (float*)smem;
    float* Lch = (float*)((char*)smem + 17408);
    bf16*  WoS = smem + 10752;          // byte 21504
    bf16*  Pe  = smem;                  // overlays dead Xch

    if (kh == 1) {   // send Of/Lf to the kh=0 partner wave
#pragma unroll
        for (int nt = 0; nt < 4; nt++)
#pragma unroll
            for (int rr = 0; rr < 4; rr++)
                Xch[(w4 * 64 + lane) * 17 + nt * 4 + rr] = Of[nt][rr];
        *(f32x4*)&Lch[(w4 * 64 + lane) * 4] = Lf;
    }
    // stage Wo^T slice from f32: WoS[c][kk] = Wo[h*64+kk][c], coalesced rows
    for (int i = tid; i < 4096; i += 512) {
        const int kk = i >> 6, c = i & 63;
        WoS[c * 72 + kk] = __float2bfloat16(Wo[(size_t)(h * 64 + kk) * 64 + c]);
    }
    __syncthreads();

    if (kh == 0) {   // combine halves
#pragma unroll
        for (int nt = 0; nt < 4; nt++)
#pragma unroll
            for (int rr = 0; rr < 4; rr++)
                Of[nt][rr] += Xch[(w4 * 64 + lane) * 17 + nt * 4 + rr];
        Lf += *(const f32x4*)&Lch[(w4 * 64 + lane) * 4];
    }
    __syncthreads();   // Xch/Lch consumed -> Pe overlay safe

    if (kh == 0) {   // normalize into Pe[w4] (Lf[rr] keyed q=quad*4+rr == Of)
        float inv_l[4];
#pragma unroll
        for (int rr = 0; rr < 4; rr++) inv_l[rr] = 1.0f / Lf[rr];
        bf16* Pew = Pe + w4 * 1152;
#pragma unroll
        for (int nt = 0; nt < 4; nt++)
#pragma unroll
            for (int rr = 0; rr < 4; rr++)
                Pew[(quad * 4 + rr) * 72 + nt * 16 + t16] =
                    __float2bfloat16(Of[nt][rr] * inv_l[rr]);
    }
    __syncthreads();   // Pe ready for both kh waves

    {   // both kh waves project their group's P: nt = kh*2 + {0,1}
        const bf16* Pew = Pe + w4 * 1152;
        const bf16x8 pf0 = *(const bf16x8*)&Pew[t16 * 72 + 0  + quad * 8];
        const bf16x8 pf1 = *(const bf16x8*)&Pew[t16 * 72 + 32 + quad * 8];

#pragma unroll
        for (int nt2 = 0; nt2 < 2; nt2++) {
            const int nt = kh * 2 + nt2;
            const bf16x8 wf0 = *(const bf16x8*)&WoS[(nt * 16 + t16) * 72 + 0  + quad * 8];
            const bf16x8 wf1 = *(const bf16x8*)&WoS[(nt * 16 + t16) * 72 + 32 + quad * 8];
            f32x4 R = (f32x4){0.f, 0.f, 0.f, 0.f};
            R = __builtin_amdgcn_mfma_f32_16x16x32_bf16(pf0, wf0, R, 0, 0, 0);
            R = __builtin_amdgcn_mfma_f32_16x16x32_bf16(pf1, wf1, R, 0, 0, 0);

            const int srow_base = qt * 64 + w4 * 16 + quad * 4;
#pragma unroll
            for (int rr = 0; rr < 4; rr++)
                atomicAdd(&out[((size_t)b * SEQ + srow_base + rr) * 64 + nt * 16 + t16],
                          R[rr]);
        }
    }
}

// ---------------------------------------------------------------------------
extern "C" void kernel_launch(void* const* d_in, const int* in_sizes, int n_in,
                              void* d_out, int out_size, void* d_ws, size_t ws_size,
                              hipStream_t stream)
{
    const float* query = (const float*)d_in[0];
    const float* key_  = (const float*)d_in[1];
    const float* value = (const float*)d_in[2];
    const float* Wq    = (const float*)d_in[3];
    const float* bq    = (const float*)d_in[4];
    const float* Wk    = (const float*)d_in[5];
    const float* bk    = (const float*)d_in[6];
    const float* Wv    = (const float*)d_in[7];
    const float* bv    = (const float*)d_in[8];
    const float* Wo    = (const float*)d_in[9];
    const float* bo    = (const float*)d_in[10];
    // d_in[11..15] dead (softmax shift-invariance)

    float* out = (float*)d_out;
    char* ws   = (char*)d_ws;
    bf16* Qh = (bf16*)(ws + (size_t) 0 * 1024 * 1024);   // [B,H,S,64]  8 MB
    bf16* Kh = (bf16*)(ws + (size_t) 8 * 1024 * 1024);   //             8 MB
    bf16* Vt = (bf16*)(ws + (size_t)16 * 1024 * 1024);   // [B,H,64,S]  8 MB

    qkv_mfma_kernel<<<dim3(64, 8, 3), 256, 0, stream>>>(
        query, key_, value, Wq, Wk, Wv, bq, bk, bv, bo, out, Qh, Kh, Vt);
    flash_attn_kernel<<<dim3(64, 16), 512, 0, stream>>>(Qh, Kh, Vt, Wo, out);
}